// Round 9
// baseline (186.972 us; speedup 1.0000x reference)
//
#include <hip/hip_runtime.h>

#define TSEQ 2048
#define DMODEL 1024
#define NHEAD 16
#define HDIM 64
#define NB 2
#define MROWS 4096   // NB*TSEQ
#define NQKV 3072    // 3*DMODEL
#define QSCALE 0.1803368801111204f  // 0.125 * log2(e): folds softmax scale+log2 into Q
#define ROPE_C (13.2877123795494f / 32.0f)  // log2(10000)/32
#define NEGINF -3.0e38f

using s16x8 = __attribute__((ext_vector_type(8))) short;
using s16x4 = __attribute__((ext_vector_type(4))) short;
using f32x4 = __attribute__((ext_vector_type(4))) float;
using f32x16 = __attribute__((ext_vector_type(16))) float;
using u32x2 = __attribute__((ext_vector_type(2))) unsigned int;
using u32x4 = __attribute__((ext_vector_type(4))) unsigned int;

static __device__ __forceinline__ float b2f(unsigned short u) {
  union { unsigned int i; float f; } x; x.i = ((unsigned int)u) << 16; return x.f;
}
static __device__ __forceinline__ unsigned short f2b(float f) {
  unsigned int u = __float_as_uint(f);
  u += 0x7fffu + ((u >> 16) & 1u);   // round-to-nearest-even
  return (unsigned short)(u >> 16);
}
// round f32 -> bf16, return as f32 BITS (low 16 zero). Sum of these == sum of
// the bf16 values actually fed to the PV MFMA (normalization consistency).
static __device__ __forceinline__ unsigned rbf(float f) {
  unsigned u = __float_as_uint(f);
  u = (u + 0x7fffu + ((u >> 16) & 1u)) & 0xffff0000u;
  return u;
}

#if __has_builtin(__builtin_amdgcn_exp2f)
#define EXP2(x) __builtin_amdgcn_exp2f(x)
#else
#define EXP2(x) exp2f(x)
#endif

// async 16B global -> LDS. LDS dest = wave-uniform base + lane*16 (m104).
typedef const __attribute__((address_space(1))) char gchar;
typedef __attribute__((address_space(3))) char lchar;
static __device__ __forceinline__ void gload_lds16(const void* g, void* l) {
  __builtin_amdgcn_global_load_lds((gchar*)g, (lchar*)l, 16, 0, 0);
}

// ---------------- 1) merged prep: x->bf16 convert + both weight transposes ----
__global__ __launch_bounds__(256) void k_prep(const float* __restrict__ x,
                                              short* __restrict__ xb,
                                              const float* __restrict__ wq,
                                              short* __restrict__ wqT,
                                              const float* __restrict__ wo,
                                              short* __restrict__ woT) {
  __shared__ float tile[32][33];
  const int blk = blockIdx.x;
  const int tid = threadIdx.x;
  if (blk < 4096) {
    const int i = blk * 256 + tid;
    const float4 v = ((const float4*)x)[i];
    s16x4 o;
    o.x = (short)f2b(v.x); o.y = (short)f2b(v.y);
    o.z = (short)f2b(v.z); o.w = (short)f2b(v.w);
    ((s16x4*)xb)[i] = o;
    return;
  }
  const float* in; short* out; int C, bx, by;
  if (blk < 7168) {
    const int l = blk - 4096; in = wq; out = wqT; C = NQKV;
    bx = l % 96; by = l / 96;
  } else {
    const int l = blk - 7168; in = wo; out = woT; C = DMODEL;
    bx = l & 31; by = l >> 5;
  }
  const int tx = tid & 31, ty4 = (tid >> 5) * 4;
#pragma unroll
  for (int i = 0; i < 4; ++i)
    tile[ty4 + i][tx] = in[(by * 32 + ty4 + i) * C + bx * 32 + tx];
  __syncthreads();
#pragma unroll
  for (int i = 0; i < 4; ++i)
    out[(bx * 32 + ty4 + i) * DMODEL + by * 32 + tx] = (short)f2b(tile[tx][ty4 + i]);
}

// ---- 2) fused QKV GEMM, T14 reg-staged single-buffer (32KB LDS) -------------
__global__ __launch_bounds__(256) void k_gemm_qkv(const short* __restrict__ A,
                                                  const short* __restrict__ BT,
                                                  short* __restrict__ Qo,
                                                  short* __restrict__ Ko,
                                                  short* __restrict__ Vt) {
  __shared__ __attribute__((aligned(16))) short As[128 * 64];   // 16 KB
  __shared__ __attribute__((aligned(16))) short Bs[128 * 64];   // 16 KB
  const int K = DMODEL;
  const int tid = threadIdx.x;
  const int wave = tid >> 6, lane = tid & 63, quad = lane >> 4, l15 = lane & 15;
  const int wm = (wave >> 1) * 64, wn = (wave & 1) * 64;
  const int bid = blockIdx.y * 24 + blockIdx.x;        // 0..767, x fastest
  const int swz = (bid & 7) * 96 + (bid >> 3);         // XCD-chunked, bijective
  const int bx = swz % 24, by = swz / 24;
  const int m0 = by * 128, n0 = bx * 128;
  f32x4 acc[4][4] = {};
  const char* Ab = (const char*)A;
  const char* Bb = (const char*)BT;
  char* AsB = (char*)As;
  char* BsB = (char*)Bs;
  int srow[4], scg[4], ssw[4];
#pragma unroll
  for (int p = 0; p < 4; ++p) {
    const int i = p * 256 + tid;
    srow[p] = i >> 3;
    scg[p] = i & 7;
    ssw[p] = scg[p] ^ (srow[p] & 7);
  }
#define QLOAD(k0v)                                                            \
  do {                                                                        \
    _Pragma("unroll")                                                         \
    for (int p = 0; p < 4; ++p) {                                             \
      ra[p] = *(const f32x4*)(Ab + ((long)(m0 + srow[p]) * K + (k0v)) * 2 + scg[p] * 16); \
      rb[p] = *(const f32x4*)(Bb + ((long)(n0 + srow[p]) * K + (k0v)) * 2 + scg[p] * 16); \
    }                                                                         \
  } while (0)
#define QWRITE()                                                              \
  do {                                                                        \
    _Pragma("unroll")                                                         \
    for (int p = 0; p < 4; ++p) {                                             \
      *(f32x4*)(AsB + srow[p] * 128 + ssw[p] * 16) = ra[p];                   \
      *(f32x4*)(BsB + srow[p] * 128 + ssw[p] * 16) = rb[p];                   \
    }                                                                         \
  } while (0)

  f32x4 ra[4], rb[4];
  const int nK = K / 64;  // 16
  QLOAD(0);
  QWRITE();
  __syncthreads();
  for (int kt = 0; kt < nK; ++kt) {
    if (kt + 1 < nK) QLOAD((kt + 1) * 64);   // prefetch issue (hides under MFMA)
#pragma unroll
    for (int hf = 0; hf < 2; ++hf) {
      s16x8 af[4], bf[4];
#pragma unroll
      for (int i = 0; i < 4; ++i) {
        const int rowa = wm + i * 16 + l15;
        af[i] = *(const s16x8*)(AsB + rowa * 128 + (((hf * 4 + quad) ^ (rowa & 7)) * 16));
        const int rowb = wn + i * 16 + l15;
        bf[i] = *(const s16x8*)(BsB + rowb * 128 + (((hf * 4 + quad) ^ (rowb & 7)) * 16));
      }
#pragma unroll
      for (int i = 0; i < 4; ++i)
#pragma unroll
        for (int j = 0; j < 4; ++j)
          acc[i][j] = __builtin_amdgcn_mfma_f32_16x16x32_bf16(af[i], bf[j], acc[i][j], 0, 0, 0);
    }
    asm volatile("s_waitcnt lgkmcnt(0)" ::: "memory");
    __builtin_amdgcn_s_barrier();            // all reads of the buffer done
    if (kt + 1 < nK) {
      QWRITE();                              // compiler inserts vmcnt for ra/rb
      asm volatile("s_waitcnt lgkmcnt(0)" ::: "memory");
      __builtin_amdgcn_s_barrier();          // writes visible to all waves
    }
  }
#undef QLOAD
#undef QWRITE
  // ---- epilogue: per-wave LDS transpose -> coalesced 16B stores ----
  const int colbase = n0 + wn;              // multiple of 64 (one head per wave)
  const int region = colbase >> 10;         // 0=Q, 1=K, 2=V
  const int hh = (colbase & 1023) >> 6;
  const int bq = m0 >> 11;                  // batch (tile never straddles)
  const int tbase = (m0 & 2047) + wm;
  char* sw = (wave < 2) ? (AsB + wave * 8192) : (BsB + (wave - 2) * 8192);
  if (region == 2) {
#pragma unroll
    for (int i = 0; i < 4; ++i)
#pragma unroll
      for (int j = 0; j < 4; ++j) {
        const int d = j * 16 + l15;
        const int t0 = i * 16 + quad * 4;
        s16x4 w;
        w.x = (short)f2b(acc[i][j][0]);
        w.y = (short)f2b(acc[i][j][1]);
        w.z = (short)f2b(acc[i][j][2]);
        w.w = (short)f2b(acc[i][j][3]);
        *(s16x4*)(sw + d * 128 + ((((t0 >> 3) ^ (d & 7))) * 16) + (t0 & 7) * 2) = w;
      }
    short* dstv = Vt + (((long)(bq * NHEAD + hh) * HDIM) << 11);
#pragma unroll
    for (int p = 0; p < 8; ++p) {
      const int linear = p * 64 + lane;
      const int d = linear >> 3, c = linear & 7;
      const s16x8 v = *(const s16x8*)(sw + d * 128 + ((c ^ (d & 7)) * 16));
      *(s16x8*)(dstv + (((long)d) << 11) + tbase + c * 8) = v;
    }
  } else {
    if (region == 1) {
#pragma unroll
      for (int i = 0; i < 4; ++i)
#pragma unroll
        for (int j = 0; j < 2; ++j) {
          const int d = j * 16 + l15;                 // 0..31
          const float inv = exp2f(-(float)d * ROPE_C);
#pragma unroll
          for (int r = 0; r < 4; ++r) {
            const int t = tbase + i * 16 + quad * 4 + r;
            float sn, cs;
            __sincosf((float)t * inv, &sn, &cs);
            const float a = acc[i][j][r];
            const float bv = acc[i][j + 2][r];
            acc[i][j][r]     = a * cs - bv * sn;
            acc[i][j + 2][r] = bv * cs + a * sn;
          }
        }
    }
#pragma unroll
    for (int i = 0; i < 4; ++i)
#pragma unroll
      for (int j = 0; j < 4; ++j)
#pragma unroll
        for (int r = 0; r < 4; ++r) {
          const int row = i * 16 + quad * 4 + r;
          const int col = j * 16 + l15;
          *(short*)(sw + row * 128 + ((((col >> 3) ^ (row & 7))) * 16) + (col & 7) * 2)
              = (short)f2b(acc[i][j][r]);
        }
    short* dst = (region ? Ko : Qo) + ((long)(bq * NHEAD + hh) * TSEQ + tbase) * HDIM;
#pragma unroll
    for (int p = 0; p < 8; ++p) {
      const int linear = p * 64 + lane;
      const int r = linear >> 3, c = linear & 7;
      const s16x8 v = *(const s16x8*)(sw + r * 128 + ((c ^ (r & 7)) * 16));
      *(s16x8*)(dst + (long)r * HDIM + c * 8) = v;
    }
  }
}

// -- 3) GEMM BMx128, BK=64, LDS dbuf + counted vmcnt (round-7 verified) -------
template <int IM, bool OUT_BF16>
__global__ __launch_bounds__(256) void k_gemm(const short* __restrict__ A,
                                              const short* __restrict__ BT,
                                              void* __restrict__ Cv,
                                              int M, int N, int K) {
  static_assert(IM == 2, "vmcnt literal assumes IM==2 (6 loads/thread)");
  __shared__ __attribute__((aligned(16))) short As[2][IM * 32 * 64];
  __shared__ __attribute__((aligned(16))) short Bs[2][128 * 64];
  const int tid = threadIdx.x;
  const int wave = tid >> 6, lane = tid & 63, quad = lane >> 4, l15 = lane & 15;
  const int wm = (wave >> 1) * (IM * 16), wn = (wave & 1) * 64;
  const int nwg = gridDim.x * gridDim.y;
  const int bid = blockIdx.y * gridDim.x + blockIdx.x;
  const int swz = (bid & 7) * (nwg >> 3) + (bid >> 3);
  const int bx = swz % gridDim.x, by = swz / gridDim.x;
  const int m0 = by * (IM * 32), n0 = bx * 128;
  f32x4 acc[IM][4] = {};
  const char* Ab = (const char*)A;
  const char* Bb = (const char*)BT;
  char* AsB = (char*)As;
  char* BsB = (char*)Bs;
  int srow[4], sg[4];
#pragma unroll
  for (int p = 0; p < 4; ++p) {
    const int i = p * 256 + tid;
    srow[p] = i >> 3;
    sg[p] = (i & 7) ^ (srow[p] & 7);
  }
#define GSTAGE(k0v, buf)                                                       \
  do {                                                                         \
    _Pragma("unroll")                                                          \
    for (int p = 0; p < IM; ++p) {                                             \
      const long go = ((long)(m0 + srow[p]) * K + (k0v)) * 2 + sg[p] * 16;     \
      gload_lds16(Ab + go, AsB + (buf) * (IM * 4096) + p * 4096 + wave * 1024);\
    }                                                                          \
    _Pragma("unroll")                                                          \
    for (int p = 0; p < 4; ++p) {                                              \
      const long go = ((long)(n0 + srow[p]) * K + (k0v)) * 2 + sg[p] * 16;     \
      gload_lds16(Bb + go, BsB + (buf) * 16384 + p * 4096 + wave * 1024);      \
    }                                                                          \
  } while (0)

  const int nK = K / 64;
  GSTAGE(0, 0);
  for (int kt = 0; kt < nK; ++kt) {
    const int cur = kt & 1;
    if (kt + 1 < nK) {
      GSTAGE((kt + 1) * 64, cur ^ 1);
      asm volatile("s_waitcnt vmcnt(6)" ::: "memory");  // IM+4 = 6 in flight
    } else {
      asm volatile("s_waitcnt vmcnt(0)" ::: "memory");
    }
    __builtin_amdgcn_s_barrier();
    const char* Ac = AsB + cur * (IM * 4096);
    const char* Bc = BsB + cur * 16384;
#pragma unroll
    for (int hf = 0; hf < 2; ++hf) {
      s16x8 af[IM], bf[4];
#pragma unroll
      for (int i = 0; i < IM; ++i) {
        const int rowa = wm + i * 16 + l15;
        af[i] = *(const s16x8*)(Ac + rowa * 128 + (((hf * 4 + quad) ^ (rowa & 7)) * 16));
      }
#pragma unroll
      for (int j = 0; j < 4; ++j) {
        const int rowb = wn + j * 16 + l15;
        bf[j] = *(const s16x8*)(Bc + rowb * 128 + (((hf * 4 + quad) ^ (rowb & 7)) * 16));
      }
#pragma unroll
      for (int i = 0; i < IM; ++i)
#pragma unroll
        for (int j = 0; j < 4; ++j)
          acc[i][j] = __builtin_amdgcn_mfma_f32_16x16x32_bf16(af[i], bf[j], acc[i][j], 0, 0, 0);
    }
    asm volatile("s_waitcnt lgkmcnt(0)" ::: "memory");
    __builtin_amdgcn_s_barrier();
  }
#undef GSTAGE
  if (OUT_BF16) {
#pragma unroll
    for (int i = 0; i < IM; ++i) {
      const int row = m0 + wm + i * 16 + quad * 4;
#pragma unroll
      for (int j = 0; j < 4; ++j) {
        const int col = n0 + wn + j * 16 + l15;
#pragma unroll
        for (int r = 0; r < 4; ++r)
          ((short*)Cv)[(long)(row + r) * N + col] = (short)f2b(acc[i][j][r]);
      }
    }
  } else {
    char* sw = (char*)Bs + wave * 8192;   // Bs dead after final barrier
#pragma unroll
    for (int i = 0; i < IM; ++i)
#pragma unroll
      for (int j = 0; j < 4; ++j)
#pragma unroll
        for (int r = 0; r < 4; ++r) {
          const int row = i * 16 + quad * 4 + r;   // 0..31
          const int col = j * 16 + l15;            // 0..63
          *(float*)(sw + row * 256 + ((((col >> 2) ^ (row & 7))) * 16) + (col & 3) * 4)
              = acc[i][j][r];
        }
    float* C = (float*)Cv;
#pragma unroll
    for (int p = 0; p < 8; ++p) {
      const int linear = p * 64 + lane;
      const int r = linear >> 4, c = linear & 15;
      const f32x4 v = *(const f32x4*)(sw + r * 256 + ((c ^ (r & 7)) * 16));
      *(f32x4*)(C + (long)(m0 + wm + r) * N + n0 + wn + c * 4) = v;
    }
  }
}

// ---------------- 4) flash attention v6: 32x32 MFMA + in-register P ----------
// BQ=128, 4 waves x 32 q-rows (grid/pairing/staging identical to verified v4/v5:
// 512 blocks, 2/CU, counted vmcnt(4)). mfma_f32_32x32x16_bf16 doubles FLOP per
// LDS byte; the 32x32 C layout (col=lane&31=q, row=(reg&3)+8*(reg>>2)+4*(lane>>5))
// makes each q-row's P live in 2 lanes -> P transpose = register packing + one
// shfl_xor(32) per k-slice (no P LDS, no bank conflicts); row-sum = local adds
// + one shfl_xor(32) at the end. LDS = 32KB (K/V dbuf only).
__global__ __launch_bounds__(256, 2) void k_attn(const short* __restrict__ Qg,
                                                 const short* __restrict__ Kg,
                                                 const short* __restrict__ Vg,
                                                 short* __restrict__ O) {
  __shared__ __attribute__((aligned(16))) short Ks[2][64 * 64];   // 16 KB
  __shared__ __attribute__((aligned(16))) short Vs[2][64 * 64];   // 16 KB
  const int bx = blockIdx.x, by = blockIdx.y;
  const int qi = ((by >> 4) & 1) ? (15 - bx) : bx;  // CU pairing: qi & 15-qi
  const int bh = by, b = bh >> 4, h = bh & 15;
  const int tid = threadIdx.x, wave = tid >> 6, lane = tid & 63;
  const int H = lane >> 5, q5 = lane & 31;
  const char* Kb = (const char*)(Kg + (long)bh * TSEQ * HDIM);
  const char* Vb = (const char*)(Vg + (long)bh * HDIM * TSEQ);
  const short* Qb = Qg + (long)bh * TSEQ * HDIM;
  const int qbase = qi * 128 + wave * 32;    // 32 q-rows per wave
  const int kjmax = 2 * qi + 1;              // last staged tile
  const int kjd = qbase >> 6;                // this wave's diagonal tile

  // Q B-frags: qf[dk] = Q[qbase+q5][d = dk*16 + H*8 + j], rope + QSCALE
  s16x8 qf[4];
#pragma unroll
  for (int dk = 0; dk < 4; ++dk)
    qf[dk] = *(const s16x8*)&Qb[(qbase + q5) * HDIM + dk * 16 + H * 8];
  {
    const float tf = (float)(qbase + q5);
#pragma unroll
    for (int dk = 0; dk < 2; ++dk)
#pragma unroll
      for (int j = 0; j < 8; ++j) {
        const int d = dk * 16 + H * 8 + j;   // 0..31
        const float inv = exp2f(-(float)d * ROPE_C);
        float sn, cs;
        __sincosf(tf * inv, &sn, &cs);
        sn *= QSCALE; cs *= QSCALE;
        const float a0 = b2f((unsigned short)qf[dk][j]);
        const float a1 = b2f((unsigned short)qf[dk + 2][j]);
        qf[dk][j] = (short)f2b(a0 * cs - a1 * sn);
        qf[dk + 2][j] = (short)f2b(a1 * cs + a0 * sn);
      }
  }
  f32x16 o0 = {}, o1 = {};   // O^T: d = ds*32 + (reg&3)+8*(reg>>2)+4H, q = q5
  float lsum = 0.0f;
  // staging (verified v5 pattern): 4x 16B per thread per tile
  const int r0 = tid >> 3,        g0 = (tid & 7) ^ (r0 & 7);
  const int r1 = 32 + (tid >> 3), g1 = (tid & 7) ^ (r1 & 7);
  char* KsB = (char*)Ks;
  char* VsB = (char*)Vs;
  const int ldsw = wave * 1024;  // + lane*16 by HW

#define STAGE(kjv, buf)                                                     \
  do {                                                                      \
    gload_lds16(Kb + (kjv) * 8192 + (r0 * 8 + g0) * 16,                     \
                KsB + (buf) * 8192 + ldsw);                                 \
    gload_lds16(Kb + (kjv) * 8192 + (r1 * 8 + g1) * 16,                     \
                KsB + (buf) * 8192 + 4096 + ldsw);                          \
    gload_lds16(Vb + (kjv) * 128 + r0 * (TSEQ * 2) + g0 * 16,               \
                VsB + (buf) * 8192 + ldsw);                                 \
    gload_lds16(Vb + (kjv) * 128 + r1 * (TSEQ * 2) + g1 * 16,               \
                VsB + (buf) * 8192 + 4096 + ldsw);                          \
  } while (0)

  STAGE(0, 0);

  for (int kj = 0; kj <= kjmax; ++kj) {
    const int cur = kj & 1;
    if (kj < kjmax) {
      STAGE(kj + 1, cur ^ 1);
      asm volatile("s_waitcnt vmcnt(4)" ::: "memory");  // tile kj landed
    } else {
      asm volatile("s_waitcnt vmcnt(0)" ::: "memory");
    }
    __builtin_amdgcn_s_barrier();           // publish buf[cur]
    if (kj <= kjd) {
      const char* kb = KsB + cur * 8192;
      const char* vb = VsB + cur * 8192;
      // S^T = K Q^T: A = K-frag (m=t, k=d), B = Q-frag (n=q, k=d)
      f32x16 s0 = {}, s1 = {};
      __builtin_amdgcn_s_setprio(1);
#pragma unroll
      for (int dk = 0; dk < 4; ++dk) {
        const int c = dk * 2 + H;           // 16B chunk within 128B row
        const int ta = q5;                  // ts=0 rows 0..31
        const s16x8 k0 = *(const s16x8*)(kb + ta * 128 + ((c ^ (ta & 7)) * 16));
        s0 = __builtin_amdgcn_mfma_f32_32x32x16_bf16(k0, qf[dk], s0, 0, 0, 0);
        const int tb = 32 + q5;             // ts=1 rows 32..63
        const s16x8 k1 = *(const s16x8*)(kb + tb * 128 + ((c ^ (tb & 7)) * 16));
        s1 = __builtin_amdgcn_mfma_f32_32x32x16_bf16(k1, qf[dk], s1, 0, 0, 0);
      }
      __builtin_amdgcn_s_setprio(0);
      if (kj == kjd) {  // causal mask: t = kj*64 + ts*32 + tl,  q = qbase + q5
        const int qloc = (qbase & 63) + q5;
#pragma unroll
        for (int r = 0; r < 16; ++r) {
          const int tl = (r & 3) + 8 * (r >> 2) + 4 * H;
          if (tl > qloc) s0[r] = NEGINF;
          if (tl + 32 > qloc) s1[r] = NEGINF;
        }
      }
      // p = exp2(s) rounded to bf16; pack per (ts, group g): regs 4g..4g+3
      unsigned pk[16];
      float ps = 0.0f;
#define PEXP(SV, TS)                                                        \
      {                                                                     \
        _Pragma("unroll")                                                   \
        for (int g = 0; g < 4; ++g) {                                       \
          const unsigned u0 = rbf(EXP2(SV[4 * g + 0]));                     \
          const unsigned u1 = rbf(EXP2(SV[4 * g + 1]));                     \
          const unsigned u2 = rbf(EXP2(SV[4 * g + 2]));                     \
          const unsigned u3 = rbf(EXP2(SV[4 * g + 3]));                     \
          ps += __uint_as_float(u0) + __uint_as_float(u1) +                 \
                __uint_as_float(u2) + __uint_as_float(u3);                  \
          pk[(TS) * 8 + g * 2]     = (u0 >> 16) | u1;                       \
          pk[(TS) * 8 + g * 2 + 1] = (u2 >> 16) | u3;                       \
        }                                                                   \
      }
      PEXP(s0, 0)
      PEXP(s1, 1)
#undef PEXP
      lsum += ps;
      // PV: O^T += V^T P^T. B-frag (n=q, k=t) assembled in-register:
      // target needs t = ks*16 + H*8 + j; elems j0..3 from lower-half lane's
      // reg-group (2*(ks&1)+H_t), j4..7 from upper-half lane's same group.
      // One shfl_xor(32) pair per ks exchanges the cross-half groups.
#pragma unroll
      for (int ks = 0; ks < 4; ++ks) {
        const int t8 = (ks >> 1) * 8;        // ts block in pk
        const int a = (ks & 1) * 2;          // groups a (lower-tgt), a+1 (upper-tgt)
        const unsigned gA0 = pk[t8 + 2 * a + 0], gA1 = pk[t8 + 2 * a + 1];
        const unsigned gB0 = pk[t8 + 2 * (a + 1) + 0], gB1 = pk[t8 + 2 * (a + 1) + 1];
        const unsigned keep0 = H ? gB0 : gA0, keep1 = H ? gB1 : gA1;
        const unsigned send0 = H ? gA0 : gB0, send1 = H ? gA1 : gB1;
        const unsigned recv0 = __shfl_xor(send0, 32);
        const unsigned recv1 = __shfl_xor(send1, 32);
        union { u32x4 u; s16x8 s; } bp;
        bp.u.x = H ? recv0 : keep0;   // elems 0-3: lower-half source
        bp.u.y = H ? recv1 : keep1;
        bp.u.z = H ? keep0 : recv0;   // elems 4-7: upper-half source
        bp.u.w = H ? keep1 : recv1;
        const int c = ks * 2 + H;     // V chunk: t0 = ks*16 + H*8
        const int da = q5;            // ds=0 rows (d 0..31)
        const s16x8 v0 = *(const s16x8*)(vb + da * 128 + ((c ^ (da & 7)) * 16));
        const int db = 32 + q5;       // ds=1 rows (d 32..63)
        const s16x8 v1 = *(const s16x8*)(vb + db * 128 + ((c ^ (db & 7)) * 16));
        __builtin_amdgcn_s_setprio(1);
        o0 = __builtin_amdgcn_mfma_f32_32x32x16_bf16(v0, bp.s, o0, 0, 0, 0);
        o1 = __builtin_amdgcn_mfma_f32_32x32x16_bf16(v1, bp.s, o1, 0, 0, 0);
        __builtin_amdgcn_s_setprio(0);
      }
    }
    asm volatile("s_waitcnt lgkmcnt(0)" ::: "memory");
    __builtin_amdgcn_s_barrier();           // all reads of buf[cur] done
  }
#undef STAGE
  // halves hold disjoint t-sets for the same q -> one exchange completes sum
  lsum += __shfl_xor(lsum, 32);
  const float rinv = 1.0f / lsum;
  const int t = qbase + q5;
  short* Orow = O + (long)(b * TSEQ + t) * DMODEL + h * HDIM;
#pragma unroll
  for (int rr = 0; rr < 4; ++rr) {
    const int d0 = 8 * rr + 4 * H;
    s16x4 w0, w1;
    w0.x = (short)f2b(o0[4 * rr + 0] * rinv);
    w0.y = (short)f2b(o0[4 * rr + 1] * rinv);
    w0.z = (short)f2b(o0[4 * rr + 2] * rinv);
    w0.w = (short)f2b(o0[4 * rr + 3] * rinv);
    *(s16x4*)(Orow + d0) = w0;
    w1.x = (short)f2b(o1[4 * rr + 0] * rinv);
    w1.y = (short)f2b(o1[4 * rr + 1] * rinv);
    w1.z = (short)f2b(o1[4 * rr + 2] * rinv);
    w1.w = (short)f2b(o1[4 * rr + 3] * rinv);
    *(s16x4*)(Orow + 32 + d0) = w1;
  }
}

// ---------------- launch ----------------
extern "C" void kernel_launch(void* const* d_in, const int* in_sizes, int n_in,
                              void* d_out, int out_size, void* d_ws, size_t ws_size,
                              hipStream_t stream) {
  const float* x = (const float*)d_in[0];      // [2,2048,1024]
  const float* w_qkv = (const float*)d_in[1];  // [1024,3072]
  const float* w_out = (const float*)d_in[2];  // [1024,1024]
  float* out = (float*)d_out;                  // [2,2048,1024]
  char* ws = (char*)d_ws;

  short* xb    = (short*)(ws);                        //  8 MiB
  short* wqkvT = (short*)(ws + (8ll << 20));          //  6 MiB
  short* woutT = (short*)(ws + (14ll << 20));         //  2 MiB
  short* Qb    = (short*)(ws + (16ll << 20));         //  8 MiB
  short* Kb    = (short*)(ws + (24ll << 20));         //  8 MiB
  short* Vt    = (short*)(ws + (32ll << 20));         //  8 MiB
  short* Ob    = (short*)(ws + (40ll << 20));         //  8 MiB  (total 48 MiB)

  k_prep<<<dim3(8192), dim3(256), 0, stream>>>(x, xb, w_qkv, wqkvT, w_out, woutT);
  k_gemm_qkv<<<dim3(NQKV / 128, MROWS / 128), dim3(256), 0, stream>>>(
      xb, wqkvT, Qb, Kb, Vt);
  k_attn<<<dim3(TSEQ / 128, NB * NHEAD), dim3(256), 0, stream>>>(Qb, Kb, Vt, Ob);
  k_gemm<2, false><<<dim3(DMODEL / 128, MROWS / 64), dim3(256), 0, stream>>>(
      Ob, woutT, (void*)out, MROWS, DMODEL, DMODEL);
}